// Round 5
// baseline (1751.875 us; speedup 1.0000x reference)
//
#include <hip/hip_runtime.h>
#include <stdint.h>

typedef unsigned short ushort_t;
typedef unsigned int uint32;

// ---------- sizes (fixed by the problem) ----------
#define NT 20000
#define NC 200000
#define NF 40000
#define E_HC 200000
#define E_BT 200000
#define E_IS 80000
#define E_PT 80000
#define FDIM 256   // H*D
#define NHEAD 4
#define DHEAD 64

// concatenated CSR index space
#define B_HC 0
#define B_BT (NC)
#define B_IS (NC + NT)
#define B_PT (NC + NT + NF)
#define NTOT (2 * NC + NT + NF)            // 460000
#define EB_BT (E_HC)
#define EB_IS (E_HC + E_BT)
#define EB_PT (E_HC + E_BT + E_IS)
#define ETOT  (E_HC + E_BT + E_IS + E_PT)  // 560000

typedef _Float16 __attribute__((ext_vector_type(8))) half8;
typedef __attribute__((ext_vector_type(4))) float f32x4;

// ---------- helpers ----------
__device__ __forceinline__ ushort_t f2h(float f) {
    _Float16 h = (_Float16)f;       // v_cvt_f16_f32, RNE
    ushort_t v;
    __builtin_memcpy(&v, &h, 2);
    return v;
}
__device__ __forceinline__ float h2f_u(ushort_t v) {
    _Float16 h;
    __builtin_memcpy(&h, &v, 2);
    return (float)h;
}
__device__ __forceinline__ float hlo(uint32 u) { return h2f_u((ushort_t)(u & 0xffffu)); }
__device__ __forceinline__ float hhi(uint32 u) { return h2f_u((ushort_t)(u >> 16)); }
__device__ __forceinline__ float finclamp(float v) {
    // NaN -> -1e30 (finite); +-inf -> +-1e30. No-op for sane values.
    return fminf(fmaxf(v, -1e30f), 1e30f);
}

union U16x8 { ushort_t u[8]; uint4 q; };

// ---------- weight pack kernels (fp32 -> fp16, transposed to [N][K]) ----------
__global__ void pack_layer_k(const float* __restrict__ Wl, const float* __restrict__ Wr,
                             ushort_t* __restrict__ ct, ushort_t* __restrict__ cc,
                             ushort_t* __restrict__ cf, int K) {
    int i = blockIdx.x * 256 + threadIdx.x;
    int per = K * 256;
    if (i >= 8 * per) return;
    int s = i / per, r = i - s * per;
    int k = r >> 8, n = r & 255;
    const float* src; ushort_t* dst; int col;
    switch (s) {
        case 0: src = Wl + 0 * per; dst = ct; col = n;        break;
        case 1: src = Wr + 1 * per; dst = ct; col = 256 + n;  break;
        case 2: src = Wr + 0 * per; dst = cc; col = n;        break;
        case 3: src = Wl + 1 * per; dst = cc; col = 256 + n;  break;
        case 4: src = Wl + 2 * per; dst = cc; col = 512 + n;  break;
        case 5: src = Wr + 3 * per; dst = cc; col = 768 + n;  break;
        case 6: src = Wr + 2 * per; dst = cf; col = n;        break;
        default: src = Wl + 3 * per; dst = cf; col = 256 + n; break;
    }
    dst[(size_t)col * K + k] = f2h(src[(size_t)k * 256 + n]);
}

__global__ void pack_out_k(const float* __restrict__ W, ushort_t* __restrict__ Wt) {
    int i = blockIdx.x * 256 + threadIdx.x;
    if (i >= 3 * 65536) return;
    int t = i >> 16, r = i & 65535;
    int k = r >> 8, n = r & 255;
    Wt[(size_t)t * 65536 + n * 256 + k] = f2h(W[(size_t)t * 65536 + k * 256 + n]);
}

__global__ void pack_lin_k(const float* __restrict__ W, ushort_t* __restrict__ Wt) {
    int i = blockIdx.x * 256 + threadIdx.x;
    if (i >= 3 * 16384) return;
    int t = i >> 14, r = i & 16383;
    int k = r >> 6, n = r & 63;
    Wt[(size_t)t * 16384 + n * 256 + k] = f2h(W[(size_t)t * 16384 + k * 64 + n]);
}

// ---------- A-resident MFMA GEMM ----------
// C[M,N] = A[M,K](fp16) @ Wt[N,K](fp16) + bias. K template (64 or 256).
// A panel [128][K] staged ONCE into LDS (swizzle slot^=row&7), then the
// N-blocks loop internally staging only the 8KB B tile -> A fetched 1x from HBM.
// 4 waves 2x2; each 64x64 via 4x4 16x16x32_f16 frags. CT: 0=f32 out, 1=f16 out.
template<int CT, int K>
__global__ __launch_bounds__(256) void gemm_ares_k(
    const ushort_t* __restrict__ A, const ushort_t* __restrict__ Wt,
    const float* __restrict__ bias, void* __restrict__ Cv,
    int M, int N, int NBY)
{
    extern __shared__ __align__(16) ushort_t lds[];
    ushort_t* As = lds;                  // [128][K]
    ushort_t* Bs = lds + 128 * K;        // [128][32]
    const int t = threadIdx.x;
    const int lane = t & 63;
    const int w = t >> 6;
    const int wr = (w >> 1) * 64, wc = (w & 1) * 64;
    const int m0 = blockIdx.x * 128;
    const int lm = lane & 15, g = lane >> 4;
    constexpr int KS = K >> 3;           // 16B slots per A row

    for (int c = t; c < 128 * KS; c += 256) {
        int row = c / KS, slot = c - row * KS;
        int grow = m0 + row;
        uint4 q = make_uint4(0u, 0u, 0u, 0u);
        if (grow < M)
            q = *reinterpret_cast<const uint4*>(A + (size_t)grow * K + slot * 8);
        *reinterpret_cast<uint4*>(&As[row * K + (slot ^ (row & 7)) * 8]) = q;
    }
    const int sr = t >> 1;
    const int ss = (t & 1) * 2;
    const int sw = (sr >> 1) & 3;
    __syncthreads();

    for (int nb = 0; nb < NBY; ++nb) {
        const int n0 = (blockIdx.y * NBY + nb) << 7;
        f32x4 acc[4][4];
#pragma unroll
        for (int mi = 0; mi < 4; mi++)
#pragma unroll
            for (int ni = 0; ni < 4; ni++) acc[mi][ni] = (f32x4){0.f, 0.f, 0.f, 0.f};

#pragma unroll
        for (int kk = 0; kk < K / 32; ++kk) {
            const int k0 = kk * 32;
            {
                const uint4* pb = reinterpret_cast<const uint4*>(
                    Wt + (size_t)(n0 + sr) * K + k0 + ss * 8);
                uint4 b0 = pb[0], b1 = pb[1];
                *reinterpret_cast<uint4*>(&Bs[sr * 32 + ((ss + 0) ^ sw) * 8]) = b0;
                *reinterpret_cast<uint4*>(&Bs[sr * 32 + ((ss + 1) ^ sw) * 8]) = b1;
            }
            __syncthreads();
            half8 af[4], bf[4];
#pragma unroll
            for (int mi = 0; mi < 4; mi++) {
                int row = wr + mi * 16 + lm;
                af[mi] = *reinterpret_cast<const half8*>(
                    &As[row * K + ((kk * 4 + g) ^ (row & 7)) * 8]);
            }
#pragma unroll
            for (int ni = 0; ni < 4; ni++) {
                int row = wc + ni * 16 + lm;
                bf[ni] = *reinterpret_cast<const half8*>(
                    &Bs[row * 32 + (g ^ ((row >> 1) & 3)) * 8]);
            }
#pragma unroll
            for (int mi = 0; mi < 4; mi++)
#pragma unroll
                for (int ni = 0; ni < 4; ni++)
                    acc[mi][ni] = __builtin_amdgcn_mfma_f32_16x16x32_f16(
                        af[mi], bf[ni], acc[mi][ni], 0, 0, 0);
            __syncthreads();
        }

#pragma unroll
        for (int mi = 0; mi < 4; mi++) {
#pragma unroll
            for (int j = 0; j < 4; j++) {
                int row = m0 + wr + mi * 16 + g * 4 + j;
                if (row >= M) continue;
#pragma unroll
                for (int ni = 0; ni < 4; ni++) {
                    int col = n0 + wc + ni * 16 + lm;
                    float v = acc[mi][ni][j];
                    if (bias) v += bias[col];
                    v = finclamp(v);
                    if (CT == 0) {
                        ((float*)Cv)[(size_t)row * N + col] = v;
                    } else {
                        ((ushort_t*)Cv)[(size_t)row * N + col] = f2h(v);
                    }
                }
            }
        }
    }
}

// ---------- MFMA input projection: C[M,64] = leaky(A_f32[M,K] @ Wt[64,K] + b) ----------
__global__ __launch_bounds__(256) void gemm_in_k(
    const float* __restrict__ A, const ushort_t* __restrict__ Wt,
    const float* __restrict__ bias, ushort_t* __restrict__ C, int M, int K)
{
    __shared__ __align__(16) ushort_t As[128][32];
    __shared__ __align__(16) ushort_t Bs[64][32];
    const int t = threadIdx.x;
    const int lane = t & 63;
    const int w = t >> 6;
    const int m0 = blockIdx.x * 128;
    const int lm = lane & 15, g = lane >> 4;

    f32x4 acc[2][4];
#pragma unroll
    for (int mi = 0; mi < 2; mi++)
#pragma unroll
        for (int ni = 0; ni < 4; ni++) acc[mi][ni] = (f32x4){0.f, 0.f, 0.f, 0.f};

    const int sr = t >> 1;
    const int ss = (t & 1) * 2;
    const int sw = (sr >> 1) & 3;
    const int br = t >> 2;
    const int bs = t & 3;
    const int bw = (br >> 1) & 3;

    for (int k0 = 0; k0 < K; k0 += 32) {
        {
            int row = m0 + sr;
            U16x8 a, b;
            if (row < M) {
                const float4* p = reinterpret_cast<const float4*>(
                    A + (size_t)row * K + k0 + (t & 1) * 16);
                float4 q0 = p[0], q1 = p[1], q2 = p[2], q3 = p[3];
                a.u[0] = f2h(q0.x); a.u[1] = f2h(q0.y); a.u[2] = f2h(q0.z); a.u[3] = f2h(q0.w);
                a.u[4] = f2h(q1.x); a.u[5] = f2h(q1.y); a.u[6] = f2h(q1.z); a.u[7] = f2h(q1.w);
                b.u[0] = f2h(q2.x); b.u[1] = f2h(q2.y); b.u[2] = f2h(q2.z); b.u[3] = f2h(q2.w);
                b.u[4] = f2h(q3.x); b.u[5] = f2h(q3.y); b.u[6] = f2h(q3.z); b.u[7] = f2h(q3.w);
            } else {
                a.q = make_uint4(0u, 0u, 0u, 0u); b.q = a.q;
            }
            *reinterpret_cast<uint4*>(&As[sr][((ss + 0) ^ sw) * 8]) = a.q;
            *reinterpret_cast<uint4*>(&As[sr][((ss + 1) ^ sw) * 8]) = b.q;
        }
        {
            uint4 q = *reinterpret_cast<const uint4*>(
                Wt + (size_t)br * K + k0 + bs * 8);
            *reinterpret_cast<uint4*>(&Bs[br][(bs ^ bw) * 8]) = q;
        }
        __syncthreads();
        half8 af[2], bf[4];
#pragma unroll
        for (int mi = 0; mi < 2; mi++) {
            int row = w * 32 + mi * 16 + lm;
            af[mi] = *reinterpret_cast<const half8*>(
                &As[row][(g ^ ((row >> 1) & 3)) * 8]);
        }
#pragma unroll
        for (int ni = 0; ni < 4; ni++) {
            int row = ni * 16 + lm;
            bf[ni] = *reinterpret_cast<const half8*>(
                &Bs[row][(g ^ ((row >> 1) & 3)) * 8]);
        }
#pragma unroll
        for (int mi = 0; mi < 2; mi++)
#pragma unroll
            for (int ni = 0; ni < 4; ni++)
                acc[mi][ni] = __builtin_amdgcn_mfma_f32_16x16x32_f16(
                    af[mi], bf[ni], acc[mi][ni], 0, 0, 0);
        __syncthreads();
    }

#pragma unroll
    for (int mi = 0; mi < 2; mi++) {
#pragma unroll
        for (int j = 0; j < 4; j++) {
            int row = m0 + w * 32 + mi * 16 + g * 4 + j;
            if (row >= M) continue;
#pragma unroll
            for (int ni = 0; ni < 4; ni++) {
                int col = ni * 16 + lm;
                float v = acc[mi][ni][j] + bias[col];
                v = (v > 0.f) ? v : 0.01f * v;
                C[(size_t)row * 64 + col] = f2h(finclamp(v));
            }
        }
    }
}

// ---------- fused CSR build over the concatenated 4-type index space ----------
__global__ void zero_cc_k(int* __restrict__ cnt, int* __restrict__ cur) {
    int i = blockIdx.x * 256 + threadIdx.x;
    if (i < NTOT) { cnt[i] = 0; cur[i] = 0; }
}

__global__ void hist4_k(const int* __restrict__ dhc, const int* __restrict__ dbt,
                        const int* __restrict__ dis, const int* __restrict__ dpt,
                        int* __restrict__ cnt) {
    int e = blockIdx.x * 256 + threadIdx.x;
    if (e >= ETOT) return;
    int idx;
    if (e < EB_BT)      idx = B_HC + dhc[e];
    else if (e < EB_IS) idx = B_BT + dbt[e - EB_BT];
    else if (e < EB_PT) idx = B_IS + dis[e - EB_IS];
    else                idx = B_PT + dpt[e - EB_PT];
    atomicAdd(&cnt[idx], 1);
}

// 3-phase exclusive scan, 8 elems/thread (8192/block; NTOT -> 57 blocks <= 64)
__global__ __launch_bounds__(1024) void scan_blk8_k(const int* __restrict__ cnt,
                                                    int* __restrict__ off,
                                                    int* __restrict__ bsum, int n) {
    __shared__ int wsum[16];
    int t = threadIdx.x, lane = t & 63, w = t >> 6;
    int i = blockIdx.x * 8192 + t * 8;
    int v[8];
#pragma unroll
    for (int k = 0; k < 8; k++) v[k] = (i + k < n) ? cnt[i + k] : 0;
    int ts = 0;
#pragma unroll
    for (int k = 0; k < 8; k++) ts += v[k];
    int x = ts;
#pragma unroll
    for (int sh = 1; sh < 64; sh <<= 1) {
        int y = __shfl_up(x, sh);
        if (lane >= sh) x += y;
    }
    if (lane == 63) wsum[w] = x;
    __syncthreads();
    int wbase = 0;
    for (int k = 0; k < w; k++) wbase += wsum[k];
    int excl = wbase + (x - ts);
#pragma unroll
    for (int k = 0; k < 8; k++) {
        if (i + k < n) off[i + k] = excl;
        excl += v[k];
    }
    if (t == 1023) bsum[blockIdx.x] = wbase + x;
}

__global__ void scan_top_k(int* __restrict__ bsum, int* __restrict__ off,
                           int n, int nb) {
    int lane = threadIdx.x;
    int v = (lane < nb) ? bsum[lane] : 0;
    int x = v;
#pragma unroll
    for (int sh = 1; sh < 64; sh <<= 1) {
        int y = __shfl_up(x, sh);
        if (lane >= sh) x += y;
    }
    if (lane < nb) bsum[lane] = x - v;
    if (lane == 63) off[n] = x;
}

__global__ void scan_fix8_k(int* __restrict__ off, const int* __restrict__ bsum, int n) {
    int i = blockIdx.x * 256 + threadIdx.x;
    if (i < n) off[i] += bsum[i >> 13];
}

__global__ void perm4_k(const int* __restrict__ shc, const int* __restrict__ dhc,
                        const int* __restrict__ sbt, const int* __restrict__ dbt,
                        const int* __restrict__ sis, const int* __restrict__ dis,
                        const int* __restrict__ spt, const int* __restrict__ dpt,
                        const int* __restrict__ off, int* __restrict__ cur,
                        int* __restrict__ ssrc) {
    int e = blockIdx.x * 256 + threadIdx.x;
    if (e >= ETOT) return;
    int idx, sv;
    if (e < EB_BT)      { idx = B_HC + dhc[e];            sv = shc[e]; }
    else if (e < EB_IS) { int l = e - EB_BT; idx = B_BT + dbt[l]; sv = sbt[l]; }
    else if (e < EB_PT) { int l = e - EB_IS; idx = B_IS + dis[l]; sv = sis[l]; }
    else                { int l = e - EB_PT; idx = B_PT + dpt[l]; sv = spt[l]; }
    int slot = atomicAdd(&cur[idx], 1);
    ssrc[off[idx] + slot] = sv;
}

// ---------- fused GATv2 gather + bias + ELU + fp16 store ----------
__device__ __forceinline__ void gat_accum(
    const ushort_t* __restrict__ xl, int ldl,
    const ushort_t* __restrict__ xr, int ldr,
    const float* __restrict__ att, const int* __restrict__ off,
    const int* __restrict__ ssrc, int d, int f,
    float& o0, float& o1, float& o2, float& o3)
{
    int j0 = off[d], j1 = off[d + 1];
    if (j0 == j1) return;                       // empty segment: msg = 0
    float4 qa = *reinterpret_cast<const float4*>(att + f);
    uint2 qr = *reinterpret_cast<const uint2*>(xr + (size_t)d * ldr + f);
    float r0 = hlo(qr.x), r1 = hhi(qr.x), r2 = hlo(qr.y), r3 = hhi(qr.y);
    float m = -1e30f, den = 0.f;
    float a0 = 0.f, a1 = 0.f, a2 = 0.f, a3 = 0.f;
    for (int j = j0; j < j1; ++j) {
        int s = ssrc[j];
        uint2 ql = *reinterpret_cast<const uint2*>(xl + (size_t)s * ldl + f);
        float l0 = hlo(ql.x), l1 = hhi(ql.x), l2 = hlo(ql.y), l3 = hhi(ql.y);
        float v0 = l0 + r0, v1 = l1 + r1, v2 = l2 + r2, v3 = l3 + r3;
        v0 = (v0 > 0.f) ? v0 : 0.2f * v0;
        v1 = (v1 > 0.f) ? v1 : 0.2f * v1;
        v2 = (v2 > 0.f) ? v2 : 0.2f * v2;
        v3 = (v3 > 0.f) ? v3 : 0.2f * v3;
        float lg = qa.x * v0 + qa.y * v1 + qa.z * v2 + qa.w * v3;
        lg += __shfl_xor(lg, 1);
        lg += __shfl_xor(lg, 2);
        lg += __shfl_xor(lg, 4);
        lg += __shfl_xor(lg, 8);
        float mn = fmaxf(m, lg);
        float sc = expf(m - mn);
        float z  = expf(lg - mn);
        den = den * sc + z;
        a0 = a0 * sc + z * l0;
        a1 = a1 * sc + z * l1;
        a2 = a2 * sc + z * l2;
        a3 = a3 * sc + z * l3;
        m = mn;
    }
    float inv = (den > 0.f) ? 1.f / den : 0.f;
    o0 += finclamp(a0 * inv);
    o1 += finclamp(a1 * inv);
    o2 += finclamp(a2 * inv);
    o3 += finclamp(a3 * inv);
}

__global__ __launch_bounds__(256) void gat_gather2_k(
    const ushort_t* __restrict__ xl1, int ldl1,
    const ushort_t* __restrict__ xr1, int ldr1,
    const float* __restrict__ att1, const int* __restrict__ off1,
    const int* __restrict__ ssrc1,
    const ushort_t* __restrict__ xl2, int ldl2,
    const ushort_t* __restrict__ xr2, int ldr2,
    const float* __restrict__ att2, const int* __restrict__ off2,
    const int* __restrict__ ssrc2,
    const float* __restrict__ b1, const float* __restrict__ b2,
    float scale, ushort_t* __restrict__ xout, int Nd)
{
    int d = blockIdx.x * 4 + (threadIdx.x >> 6);
    if (d >= Nd) return;
    int lane = threadIdx.x & 63;
    int f = lane * 4;
    float o0 = 0.f, o1 = 0.f, o2 = 0.f, o3 = 0.f;
    gat_accum(xl1, ldl1, xr1, ldr1, att1, off1, ssrc1, d, f, o0, o1, o2, o3);
    if (off2) gat_accum(xl2, ldl2, xr2, ldr2, att2, off2, ssrc2, d, f, o0, o1, o2, o3);
    float4 bv = *reinterpret_cast<const float4*>(b1 + f);
    o0 += bv.x; o1 += bv.y; o2 += bv.z; o3 += bv.w;
    if (b2) {
        float4 b2v = *reinterpret_cast<const float4*>(b2 + f);
        o0 += b2v.x; o1 += b2v.y; o2 += b2v.z; o3 += b2v.w;
    }
    o0 *= scale; o1 *= scale; o2 *= scale; o3 *= scale;
    o0 = (o0 > 0.f) ? o0 : (expf(o0) - 1.f);
    o1 = (o1 > 0.f) ? o1 : (expf(o1) - 1.f);
    o2 = (o2 > 0.f) ? o2 : (expf(o2) - 1.f);
    o3 = (o3 > 0.f) ? o3 : (expf(o3) - 1.f);
    uint32 lo = ((uint32)f2h(finclamp(o1)) << 16) | (uint32)f2h(finclamp(o0));
    uint32 hi = ((uint32)f2h(finclamp(o3)) << 16) | (uint32)f2h(finclamp(o2));
    *reinterpret_cast<uint2*>(xout + (size_t)d * FDIM + f) = make_uint2(lo, hi);
}

// ---------- host launch ----------
extern "C" void kernel_launch(void* const* d_in, const int* in_sizes, int n_in,
                              void* d_out, int out_size, void* d_ws, size_t ws_size,
                              hipStream_t stream) {
    (void)in_sizes; (void)n_in; (void)out_size;
    const float* x_table = (const float*)d_in[0];
    const float* x_column = (const float*)d_in[1];
    const float* x_fk = (const float*)d_in[2];
    const float* lin_w = (const float*)d_in[3];   // [3,256,64]
    const float* lin_b = (const float*)d_in[4];   // [3,64]
    const float* out_w = (const float*)d_in[5];   // [3,256,256]
    const float* out_b = (const float*)d_in[6];   // [3,256]
    const float* Wl0 = (const float*)d_in[7];     // [4,64,256]
    const float* Wr0 = (const float*)d_in[8];
    const float* att0 = (const float*)d_in[9];    // [4,4,64]
    const float* b0 = (const float*)d_in[10];     // [4,256]
    const float* Wl1 = (const float*)d_in[11];    // [4,256,256]
    const float* Wr1 = (const float*)d_in[12];
    const float* att1 = (const float*)d_in[13];
    const float* b1 = (const float*)d_in[14];
    const int* src_hc = (const int*)d_in[15];
    const int* dst_hc = (const int*)d_in[16];
    const int* src_bt = (const int*)d_in[17];
    const int* dst_bt = (const int*)d_in[18];
    const int* src_is = (const int*)d_in[19];
    const int* dst_is = (const int*)d_in[20];
    const int* src_pt = (const int*)d_in[21];
    const int* dst_pt = (const int*)d_in[22];
    float* out = (float*)d_out;

    // raise dynamic-LDS cap for the A-resident GEMM (72 KB for K=256)
    static bool attr_done = false;
    if (!attr_done) {
        int sz256 = 128 * 256 * 2 + 128 * 32 * 2;
        int sz64  = 128 * 64 * 2 + 128 * 32 * 2;
        hipFuncSetAttribute(reinterpret_cast<const void*>(&gemm_ares_k<1, 256>),
                            hipFuncAttributeMaxDynamicSharedMemorySize, sz256);
        hipFuncSetAttribute(reinterpret_cast<const void*>(&gemm_ares_k<0, 256>),
                            hipFuncAttributeMaxDynamicSharedMemorySize, sz256);
        hipFuncSetAttribute(reinterpret_cast<const void*>(&gemm_ares_k<1, 64>),
                            hipFuncAttributeMaxDynamicSharedMemorySize, sz64);
        attr_done = true;
    }

    // ---- carve workspace (~615 MB) ----
    char* p = (char*)d_ws;
    auto alloc = [&](size_t bytes) -> char* {
        char* r = p;
        p += (bytes + 255) & ~(size_t)255;
        return r;
    };
    ushort_t* xt = (ushort_t*)alloc((size_t)NT * FDIM * 2);
    ushort_t* xc = (ushort_t*)alloc((size_t)NC * FDIM * 2);
    ushort_t* xf = (ushort_t*)alloc((size_t)NF * FDIM * 2);
    ushort_t* pt_buf = (ushort_t*)alloc((size_t)NT * 512 * 2);
    ushort_t* pc_buf = (ushort_t*)alloc((size_t)NC * 1024 * 2);
    ushort_t* pf_buf = (ushort_t*)alloc((size_t)NF * 512 * 2);
    int* off_cat = (int*)alloc((size_t)(NTOT + 1) * 4);
    int* ssrc_cat = (int*)alloc((size_t)ETOT * 4);
    int* cnt = (int*)alloc((size_t)NTOT * 4);
    int* cur = (int*)alloc((size_t)NTOT * 4);
    int* bsum = (int*)alloc((size_t)64 * 4);
    ushort_t* wcat_t0 = (ushort_t*)alloc((size_t)512 * 64 * 2);
    ushort_t* wcat_c0 = (ushort_t*)alloc((size_t)1024 * 64 * 2);
    ushort_t* wcat_f0 = (ushort_t*)alloc((size_t)512 * 64 * 2);
    ushort_t* wcat_t1 = (ushort_t*)alloc((size_t)512 * 256 * 2);
    ushort_t* wcat_c1 = (ushort_t*)alloc((size_t)1024 * 256 * 2);
    ushort_t* wcat_f1 = (ushort_t*)alloc((size_t)512 * 256 * 2);
    ushort_t* owt = (ushort_t*)alloc((size_t)3 * 65536 * 2);
    ushort_t* lint = (ushort_t*)alloc((size_t)3 * 16384 * 2);
    if ((size_t)(p - (char*)d_ws) > ws_size) return;

    // ---- weight packs (once) ----
    hipLaunchKernelGGL(pack_layer_k, dim3((8 * 64 * 256 + 255) / 256), dim3(256), 0,
                       stream, Wl0, Wr0, wcat_t0, wcat_c0, wcat_f0, 64);
    hipLaunchKernelGGL(pack_layer_k, dim3((8 * 256 * 256 + 255) / 256), dim3(256), 0,
                       stream, Wl1, Wr1, wcat_t1, wcat_c1, wcat_f1, 256);
    hipLaunchKernelGGL(pack_out_k, dim3((3 * 65536 + 255) / 256), dim3(256), 0,
                       stream, out_w, owt);
    hipLaunchKernelGGL(pack_lin_k, dim3((3 * 16384 + 255) / 256), dim3(256), 0,
                       stream, lin_w, lint);

    // ---- fused CSR build (once; shared by both layers) ----
    {
        int nb = (NTOT + 8191) / 8192;   // 57 <= 64
        hipLaunchKernelGGL(zero_cc_k, dim3((NTOT + 255) / 256), dim3(256), 0, stream,
                           cnt, cur);
        hipLaunchKernelGGL(hist4_k, dim3((ETOT + 255) / 256), dim3(256), 0, stream,
                           dst_hc, dst_bt, dst_is, dst_pt, cnt);
        hipLaunchKernelGGL(scan_blk8_k, dim3(nb), dim3(1024), 0, stream,
                           cnt, off_cat, bsum, NTOT);
        hipLaunchKernelGGL(scan_top_k, dim3(1), dim3(64), 0, stream,
                           bsum, off_cat, NTOT, nb);
        hipLaunchKernelGGL(scan_fix8_k, dim3((NTOT + 255) / 256), dim3(256), 0, stream,
                           off_cat, bsum, NTOT);
        hipLaunchKernelGGL(perm4_k, dim3((ETOT + 255) / 256), dim3(256), 0, stream,
                           src_hc, dst_hc, src_bt, dst_bt, src_is, dst_is,
                           src_pt, dst_pt, off_cat, cur, ssrc_cat);
    }

    // ---- input projections: MFMA with fused fp32->fp16 cvt, N=64 ----
    hipLaunchKernelGGL(gemm_in_k, dim3((NT + 127) / 128), dim3(256), 0, stream,
                       x_table, lint + 0 * 16384, lin_b + 0 * 64, xt, NT, 256);
    hipLaunchKernelGGL(gemm_in_k, dim3((NC + 127) / 128), dim3(256), 0, stream,
                       x_column, lint + 1 * 16384, lin_b + 1 * 64, xc, NC, 256);
    hipLaunchKernelGGL(gemm_in_k, dim3((NF + 127) / 128), dim3(256), 0, stream,
                       x_fk, lint + 2 * 16384, lin_b + 2 * 64, xf, NF, 256);

    auto ares16 = [&](const ushort_t* A, const ushort_t* Wt, ushort_t* C,
                      int M, int N, int K, int gy) {
        int nby = (N >> 7) / gy;
        dim3 grid((M + 127) / 128, gy);
        if (K == 256) {
            int sz = 128 * 256 * 2 + 128 * 32 * 2;
            hipLaunchKernelGGL((gemm_ares_k<1, 256>), grid, dim3(256), sz, stream,
                               A, Wt, (const float*)nullptr, (void*)C, M, N, nby);
        } else {
            int sz = 128 * 64 * 2 + 128 * 32 * 2;
            hipLaunchKernelGGL((gemm_ares_k<1, 64>), grid, dim3(256), sz, stream,
                               A, Wt, (const float*)nullptr, (void*)C, M, N, nby);
        }
    };
    auto ares32 = [&](const ushort_t* A, const ushort_t* Wt, const float* bias,
                      float* C, int M, int N, int gy) {
        int nby = (N >> 7) / gy;
        int sz = 128 * 256 * 2 + 128 * 32 * 2;
        hipLaunchKernelGGL((gemm_ares_k<0, 256>), dim3((M + 127) / 128, gy),
                           dim3(256), sz, stream, A, Wt, bias, (void*)C, M, N, nby);
    };

    for (int l = 0; l < 2; l++) {
        const ushort_t* wt_t = l ? wcat_t1 : wcat_t0;
        const ushort_t* wt_c = l ? wcat_c1 : wcat_c0;
        const ushort_t* wt_f = l ? wcat_f1 : wcat_f0;
        const float* att = l ? att1 : att0;
        const float* bb = l ? b1 : b0;
        int Kd = l ? 256 : 64;

        // concatenated projections (xt/xc/xf fully consumed before gathers overwrite)
        ares16(xt, wt_t, pt_buf, NT, 512, Kd, 4);
        ares16(xc, wt_c, pc_buf, NC, 1024, Kd, 1);
        ares16(xf, wt_f, pf_buf, NF, 512, Kd, 2);

        // fused gathers: bias + softmax-msg(s) + ELU -> fp16 next-layer feats
        // bt -> xt
        hipLaunchKernelGGL(gat_gather2_k, dim3((NT + 3) / 4), dim3(256), 0, stream,
                           pc_buf + 256, 1024, pt_buf + 256, 512,
                           att + 1 * FDIM, off_cat + B_BT, ssrc_cat,
                           (const ushort_t*)nullptr, 0, (const ushort_t*)nullptr, 0,
                           (const float*)nullptr, (const int*)nullptr,
                           (const int*)nullptr,
                           bb + 1 * FDIM, (const float*)nullptr, 1.0f, xt, NT);
        // is -> xf
        hipLaunchKernelGGL(gat_gather2_k, dim3((NF + 3) / 4), dim3(256), 0, stream,
                           pc_buf + 512, 1024, pf_buf + 0, 512,
                           att + 2 * FDIM, off_cat + B_IS, ssrc_cat,
                           (const ushort_t*)nullptr, 0, (const ushort_t*)nullptr, 0,
                           (const float*)nullptr, (const int*)nullptr,
                           (const int*)nullptr,
                           bb + 2 * FDIM, (const float*)nullptr, 1.0f, xf, NF);
        // hc + pt -> xc (mean of the two types)
        hipLaunchKernelGGL(gat_gather2_k, dim3((NC + 3) / 4), dim3(256), 0, stream,
                           pt_buf + 0, 512, pc_buf + 0, 1024,
                           att + 0 * FDIM, off_cat + B_HC, ssrc_cat,
                           pf_buf + 256, 512, pc_buf + 768, 1024,
                           att + 3 * FDIM, off_cat + B_PT, ssrc_cat,
                           bb + 0 * FDIM, bb + 3 * FDIM, 0.5f, xc, NC);
    }

    // ---- output projections -> d_out (concat xt, xc, xf), fp32 ----
    ares32(xt, owt + 0 * 65536, out_b + 0 * 256, out, NT, 256, 2);
    ares32(xc, owt + 1 * 65536, out_b + 1 * 256, out + (size_t)NT * FDIM, NC, 256, 1);
    ares32(xf, owt + 2 * 65536, out_b + 2 * 256, out + (size_t)(NT + NC) * FDIM,
           NF, 256, 2);
}